// Round 5
// baseline (1020.673 us; speedup 1.0000x reference)
//
#include <hip/hip_runtime.h>

typedef float v2f __attribute__((ext_vector_type(2)));

#define B_   32
#define DE_  256
#define T_   32
#define C_   128
#define HW_  16384

#define HSTRIDE 257   // [c_local][row] LDS stride: 257 % 32 == 1 -> conflict-free lane-consecutive access

__device__ inline v2f vfma2(v2f a, v2f b, v2f c) {
#if __has_builtin(__builtin_elementwise_fma)
    return __builtin_elementwise_fma(a, b, c);
#else
    v2f r; r.x = fmaf(a.x, b.x, c.x); r.y = fmaf(a.y, b.y, c.y); return r;
#endif
}

// Kernel 1: e_[b][c][t] = sum_d e[b][d][t] * Wd[d][c] + bias[c]   (fp32 -> ws)
// grid (8, 32): blockIdx.x = 16-channel slab, blockIdx.y = batch. 256 threads.
__global__ __launch_bounds__(256) void dense_e_kernel(
    const float* __restrict__ e, const float* __restrict__ Wd,
    const float* __restrict__ bias, float* __restrict__ ews)
{
    __shared__ float elds[DE_ * T_];   // 32 KB, [d][t]
    __shared__ float wlds[DE_ * 16];   // 16 KB, [d][c_local]
    const int b   = blockIdx.y;
    const int cq  = blockIdx.x;        // channels [cq*16, cq*16+16)
    const int tid = threadIdx.x;       // owns d-row = tid

    {
        const float4* erow = (const float4*)(e + ((size_t)b * DE_ + tid) * T_);
        float4* edst = (float4*)(elds + tid * T_);
        #pragma unroll
        for (int i = 0; i < 8; ++i) edst[i] = erow[i];

        const float4* wrow = (const float4*)(Wd + (size_t)tid * C_ + cq * 16);
        float4* wdst = (float4*)(wlds + tid * 16);
        #pragma unroll
        for (int i = 0; i < 4; ++i) wdst[i] = wrow[i];
    }
    __syncthreads();

    const int t  = tid & 31;
    const int c8 = tid >> 5;           // 0..7
    float a0 = 0.f, a1 = 0.f;
    #pragma unroll 8
    for (int d = 0; d < DE_; ++d) {
        float ev = elds[d * T_ + t];
        a0 = fmaf(ev, wlds[d * 16 + c8],     a0);
        a1 = fmaf(ev, wlds[d * 16 + 8 + c8], a1);
    }
    const int c0 = cq * 16 + c8;
    a0 += bias[c0];
    a1 += bias[c0 + 8];
    ews[((size_t)b * C_ + c0)     * T_ + t] = a0;
    ews[((size_t)b * C_ + c0 + 8) * T_ + t] = a1;
}

// Kernel 2: fused scores + softmax(T) + context + concat copy.
// SINGLE-WAVE blocks: 64 threads, 256-row tile, R=4 rows/thread
// (rows tid, tid+64, tid+128, tid+192). No __syncthreads at all — DS ops
// within one wave are hardware-ordered, so scatter->compute and
// write->read hazards need no barriers and no vmcnt(0) drains.
// Each e_ LDS broadcast now feeds 4 rows of FMAs (1 b128 : 8 pk-FMA),
// halving pressure on the per-CU LDS pipe vs the R=2 version.
__global__ __launch_bounds__(64) void attn_fused_kernel(
    const float* __restrict__ h,
    const float* __restrict__ ews,
    float* __restrict__ out)
{
    __shared__ float hT[8 * HSTRIDE];    // 8.2 KB: transposed h chunk [c_local][row]
    __shared__ float es[2][8 * T_];      // 2 x 1 KB: double-buffered e_ slice [c_local][t]

    const int b   = blockIdx.x >> 6;                  // 32 batches
    const int n0  = (blockIdx.x & 63) << 8;           // 64 tiles x 256 rows
    const int tid = threadIdx.x;                      // 0..63 (one wave)
    const float* __restrict__ eb = ews + (size_t)b * (C_ * T_);
    const float* __restrict__ hb = h   + ((size_t)b * HW_ + n0) * C_;
    float* __restrict__       ob = out + ((size_t)b * HW_ + n0) * (2 * C_);

    v2f s[4][16];
    #pragma unroll
    for (int j = 0; j < 4; ++j)
        #pragma unroll
        for (int i = 0; i < 16; ++i) s[j][i] = (v2f){0.f, 0.f};

    // ---- Pass 1: logits, 16 chunks of 8 channels, reg-prefetched ----
    float4 hv[8];
    #pragma unroll
    for (int i = 0; i < 8; ++i) {
        const int idx = i * 64 + tid;
        hv[i] = *(const float4*)(hb + (size_t)(idx >> 1) * C_ + (idx & 1) * 4);
    }
    float4 ereg = ((const float4*)(eb))[tid];

    #pragma unroll 1
    for (int ch = 0; ch < 16; ++ch) {
        // Scatter prefetched h into hT (HW keeps DS order vs prior reads).
        #pragma unroll
        for (int i = 0; i < 8; ++i) {
            const int idx = i * 64 + tid;
            const int row = idx >> 1, c4 = idx & 1;
            float* d = hT + (c4 * 4) * HSTRIDE + row;
            d[0]           = hv[i].x;
            d[HSTRIDE]     = hv[i].y;
            d[2 * HSTRIDE] = hv[i].z;
            d[3 * HSTRIDE] = hv[i].w;
        }
        ((float4*)es[ch & 1])[tid] = ereg;

        // Concat-copy store (fire-and-forget), then prefetch next chunk.
        #pragma unroll
        for (int i = 0; i < 8; ++i) {
            const int idx = i * 64 + tid;
            const int row = idx >> 1, c4 = idx & 1;
            *(float4*)(ob + (size_t)row * (2 * C_) + C_ + ch * 8 + c4 * 4) = hv[i];
        }
        if (ch < 15) {
            #pragma unroll
            for (int i = 0; i < 8; ++i) {
                const int idx = i * 64 + tid;
                hv[i] = *(const float4*)(hb + (size_t)(idx >> 1) * C_ + (ch + 1) * 8 + (idx & 1) * 4);
            }
            ereg = ((const float4*)(eb + (ch + 1) * 8 * T_))[tid];
        }

        // Compute: h reads lane-consecutive (conflict-free); e reads are
        // uniform b128 broadcasts shared by 4 rows of FMAs.
        const float* esc = es[ch & 1];
        #pragma unroll
        for (int cl = 0; cl < 8; ++cl) {
            v2f hrv[4];
            #pragma unroll
            for (int j = 0; j < 4; ++j) {
                const float hr = hT[cl * HSTRIDE + 64 * j + tid];
                hrv[j] = (v2f){hr, hr};
            }
            const float4* ec4 = (const float4*)(esc + cl * T_);
            #pragma unroll
            for (int k = 0; k < 8; ++k) {
                const float4 ef = ec4[k];
                const v2f eA = {ef.x, ef.y}, eB = {ef.z, ef.w};
                #pragma unroll
                for (int j = 0; j < 4; ++j) {
                    s[j][2 * k]     = vfma2(hrv[j], eA, s[j][2 * k]);
                    s[j][2 * k + 1] = vfma2(hrv[j], eB, s[j][2 * k + 1]);
                }
            }
        }
    }

    // ---- Softmax over 32 logits, all 4 rows, thread-local ----
    #pragma unroll
    for (int j = 0; j < 4; ++j) {
        v2f m2 = s[j][0];
        #pragma unroll
        for (int i = 1; i < 16; ++i) { m2.x = fmaxf(m2.x, s[j][i].x); m2.y = fmaxf(m2.y, s[j][i].y); }
        const float m = fmaxf(m2.x, m2.y);
        float l = 0.f;
        #pragma unroll
        for (int i = 0; i < 16; ++i) {
            v2f p; p.x = __expf(s[j][i].x - m); p.y = __expf(s[j][i].y - m);
            s[j][i] = p; l += p.x + p.y;
        }
        const float inv = 1.0f / l;
        #pragma unroll
        for (int i = 0; i < 16; ++i) { s[j][i].x *= inv; s[j][i].y *= inv; }
    }

    // ---- Pass 2: context, 16 chunks of 8 channels, staged out via hT ----
    float4 ep = ((const float4*)(eb))[tid];
    #pragma unroll 1
    for (int ch = 0; ch < 16; ++ch) {
        ((float4*)es[ch & 1])[tid] = ep;
        if (ch < 15) ep = ((const float4*)(eb + (ch + 1) * 8 * T_))[tid];

        const float* esc = es[ch & 1];
        #pragma unroll
        for (int cl = 0; cl < 8; ++cl) {
            const float4* ec4 = (const float4*)(esc + cl * T_);
            v2f a[4];
            #pragma unroll
            for (int j = 0; j < 4; ++j) a[j] = (v2f){0.f, 0.f};
            #pragma unroll
            for (int k = 0; k < 8; ++k) {
                const float4 ef = ec4[k];
                const v2f eA = {ef.x, ef.y}, eB = {ef.z, ef.w};
                #pragma unroll
                for (int j = 0; j < 4; ++j) {
                    a[j] = vfma2(eA, s[j][2 * k], a[j]);
                    a[j] = vfma2(eB, s[j][2 * k + 1], a[j]);
                }
            }
            #pragma unroll
            for (int j = 0; j < 4; ++j)
                hT[cl * HSTRIDE + 64 * j + tid] = a[j].x + a[j].y;
        }
        // Gather + coalesced store (DS order guarantees results landed).
        #pragma unroll
        for (int i = 0; i < 8; ++i) {
            const int idx = i * 64 + tid;
            const int row = idx >> 1, c4 = idx & 1;
            const float* src = hT + (c4 * 4) * HSTRIDE + row;
            float4 st = { src[0], src[HSTRIDE], src[2 * HSTRIDE], src[3 * HSTRIDE] };
            *(float4*)(ob + (size_t)row * (2 * C_) + ch * 8 + c4 * 4) = st;
        }
    }
}

extern "C" void kernel_launch(void* const* d_in, const int* in_sizes, int n_in,
                              void* d_out, int out_size, void* d_ws, size_t ws_size,
                              hipStream_t stream) {
    const float* e    = (const float*)d_in[0];   // [B, DE, T]
    const float* h    = (const float*)d_in[1];   // [B, H, W, C]
    const float* Wd   = (const float*)d_in[2];   // [DE, C]
    const float* bias = (const float*)d_in[3];   // [C]
    float* ews = (float*)d_ws;                   // [B, C, T] fp32 (512 KB scratch)
    float* out = (float*)d_out;                  // [B, H, W, 2C] fp32

    dense_e_kernel<<<dim3(8, 32), 256, 0, stream>>>(e, Wd, bias, ews);
    attn_fused_kernel<<<dim3(32 * (HW_ / 256)), 64, 0, stream>>>(h, ews, out);
}